// Round 2
// baseline (232.298 us; speedup 1.0000x reference)
//
#include <hip/hip_runtime.h>

// TaylorActivation: out = Horner(x; c[0..8]), c = w[:,0], order 8.
// x: (512, 65536) fp32 = 33,554,432 elems. Pure streaming elementwise ->
// memory-bound. 268 MB kernel traffic; roofline ~43 us @ 6.3 TB/s.
//
// R2 post-mortem of R1 (81.4 us kernel, 2.5 TB/s):
//  - KEEP cached loads: FETCH_SIZE proved L3 serves ~half of x (67 MB vs
//    134 MB) — NT loads would forfeit that.
//  - REVERT VPT 8 -> 4: 108 VGPRs capped occupancy at 4 waves/SIMD and
//    grid 4096 gave only 16 blocks/CU -> latency-hiding failure (3.3 TB/s
//    effective). Streaming kernels want TLP over per-thread MLP.
//  - ADD __launch_bounds__(256, 8): force <=64 VGPR -> 8 waves/SIMD.
//    Register need ~35 (16 data + addr + coeffs in SGPRs) -> no spill.
//  - Stores stay nontemporal (write stream never reused; fill kernel
//    proves write path does 6.7 TB/s).

typedef float f32x4 __attribute__((ext_vector_type(4)));

#define VPT 4  // f32x4 per thread (64 B/thread)

__global__ __launch_bounds__(256, 8) void taylor_poly_kernel(
    const f32x4* __restrict__ x,
    const float* __restrict__ w,   // 9 coefficients, c[i] = w[i]
    f32x4* __restrict__ out,
    int n4)
{
    const float c0 = w[0], c1 = w[1], c2 = w[2], c3 = w[3], c4 = w[4];
    const float c5 = w[5], c6 = w[6], c7 = w[7], c8 = w[8];

    // Base for this block's VPT consecutive coalesced sweeps.
    const int base = blockIdx.x * (blockDim.x * VPT) + threadIdx.x;
    const bool full = (base + (VPT - 1) * blockDim.x) < n4;

    f32x4 v[VPT];

    if (full) {
        // Hot path: branchless, 4 independent cached 16B loads.
#pragma unroll
        for (int k = 0; k < VPT; ++k)
            v[k] = x[base + k * blockDim.x];
    } else {
#pragma unroll
        for (int k = 0; k < VPT; ++k) {
            int i = base + k * blockDim.x;
            if (i < n4) v[k] = x[i];
        }
    }

#pragma unroll
    for (int k = 0; k < VPT; ++k) {
        f32x4 r;
#pragma unroll
        for (int e = 0; e < 4; ++e) {
            float xv = v[k][e];
            float acc = fmaf(c8, xv, c7);
            acc = fmaf(acc, xv, c6);
            acc = fmaf(acc, xv, c5);
            acc = fmaf(acc, xv, c4);
            acc = fmaf(acc, xv, c3);
            acc = fmaf(acc, xv, c2);
            acc = fmaf(acc, xv, c1);
            acc = fmaf(acc, xv, c0);
            r[e] = acc;
        }
        v[k] = r;  // reuse register
    }

    if (full) {
#pragma unroll
        for (int k = 0; k < VPT; ++k)
            __builtin_nontemporal_store(v[k], &out[base + k * blockDim.x]);
    } else {
#pragma unroll
        for (int k = 0; k < VPT; ++k) {
            int i = base + k * blockDim.x;
            if (i < n4) __builtin_nontemporal_store(v[k], &out[i]);
        }
    }
}

extern "C" void kernel_launch(void* const* d_in, const int* in_sizes, int n_in,
                              void* d_out, int out_size, void* d_ws, size_t ws_size,
                              hipStream_t stream) {
    const float* x = (const float*)d_in[0];
    const float* w = (const float*)d_in[1];
    float* out = (float*)d_out;

    int n = in_sizes[0];          // 33,554,432 — divisible by 16
    int n4 = n >> 2;              // 8,388,608 f32x4

    const int block = 256;
    const int elems_per_block = block * VPT;                  // 1024 vec4 / block
    int grid = (n4 + elems_per_block - 1) / elems_per_block;  // 8192

    taylor_poly_kernel<<<grid, block, 0, stream>>>(
        (const f32x4*)x, w, (f32x4*)out, n4);
}

// Round 3
// 220.309 us; speedup vs baseline: 1.0544x; 1.0544x over previous
//
#include <hip/hip_runtime.h>

// TaylorActivation: out = Horner(x; c[0..8]), c = w[:,0], order 8.
// x: (512, 65536) fp32 = 33,554,432 elems. Pure streaming elementwise ->
// memory-bound. 268 MB kernel traffic; roofline ~43 us @ 6.3 TB/s.
//
// R3 post-mortem of R1/R2: cached loads were the regression, not occupancy.
//  - R1 (cached, VPT=8): kernel 81.4 us. R2 (cached, VPT=4, 8 waves/SIMD
//    forced): dur identical to R1 -> occupancy fix recovered nothing.
//    R0 (NT loads): kernel ~62 us. Single common factor: load policy.
//  - Mechanism: harness restores x / poisons out right before the kernel,
//    leaving ~256 MB of DIRTY lines in L3 (R1's FETCH=67MB proves x was
//    half L3-resident). Cached read-misses ALLOCATE -> evict dirty lines
//    -> hidden writeback traffic during the kernel. NT loads are
//    no-allocate but still HIT resident lines: L3 benefit without the
//    eviction cost. NT loads strictly dominate here.
//  - R3 = R2 with __builtin_nontemporal_load restored (single-variable
//    change from a measured point). Keep: VPT=4, block-uniform guard,
//    __launch_bounds__(256,8) (VPT=4 needs ~40 VGPR, fits 8 waves/SIMD).
//  - Stores stay nontemporal (write stream never reused; fill kernel
//    proves write path does 6.7 TB/s).

typedef float f32x4 __attribute__((ext_vector_type(4)));

#define VPT 4  // f32x4 per thread (64 B/thread)

__global__ __launch_bounds__(256, 8) void taylor_poly_kernel(
    const f32x4* __restrict__ x,
    const float* __restrict__ w,   // 9 coefficients, c[i] = w[i]
    f32x4* __restrict__ out,
    int n4)
{
    const float c0 = w[0], c1 = w[1], c2 = w[2], c3 = w[3], c4 = w[4];
    const float c5 = w[5], c6 = w[6], c7 = w[7], c8 = w[8];

    // Base for this block's VPT consecutive coalesced sweeps.
    const int base = blockIdx.x * (blockDim.x * VPT) + threadIdx.x;
    const bool full = (base + (VPT - 1) * blockDim.x) < n4;

    f32x4 v[VPT];

    if (full) {
        // Hot path: branchless, 4 independent nontemporal 16B loads.
#pragma unroll
        for (int k = 0; k < VPT; ++k)
            v[k] = __builtin_nontemporal_load(&x[base + k * blockDim.x]);
    } else {
#pragma unroll
        for (int k = 0; k < VPT; ++k) {
            int i = base + k * blockDim.x;
            if (i < n4) v[k] = __builtin_nontemporal_load(&x[i]);
        }
    }

#pragma unroll
    for (int k = 0; k < VPT; ++k) {
        f32x4 r;
#pragma unroll
        for (int e = 0; e < 4; ++e) {
            float xv = v[k][e];
            float acc = fmaf(c8, xv, c7);
            acc = fmaf(acc, xv, c6);
            acc = fmaf(acc, xv, c5);
            acc = fmaf(acc, xv, c4);
            acc = fmaf(acc, xv, c3);
            acc = fmaf(acc, xv, c2);
            acc = fmaf(acc, xv, c1);
            acc = fmaf(acc, xv, c0);
            r[e] = acc;
        }
        v[k] = r;  // reuse register
    }

    if (full) {
#pragma unroll
        for (int k = 0; k < VPT; ++k)
            __builtin_nontemporal_store(v[k], &out[base + k * blockDim.x]);
    } else {
#pragma unroll
        for (int k = 0; k < VPT; ++k) {
            int i = base + k * blockDim.x;
            if (i < n4) __builtin_nontemporal_store(v[k], &out[i]);
        }
    }
}

extern "C" void kernel_launch(void* const* d_in, const int* in_sizes, int n_in,
                              void* d_out, int out_size, void* d_ws, size_t ws_size,
                              hipStream_t stream) {
    const float* x = (const float*)d_in[0];
    const float* w = (const float*)d_in[1];
    float* out = (float*)d_out;

    int n = in_sizes[0];          // 33,554,432 — divisible by 16
    int n4 = n >> 2;              // 8,388,608 f32x4

    const int block = 256;
    const int elems_per_block = block * VPT;                  // 1024 vec4 / block
    int grid = (n4 + elems_per_block - 1) / elems_per_block;  // 8192

    taylor_poly_kernel<<<grid, block, 0, stream>>>(
        (const f32x4*)x, w, (f32x4*)out, n4);
}

// Round 4
// 219.656 us; speedup vs baseline: 1.0576x; 1.0030x over previous
//
#include <hip/hip_runtime.h>

// TaylorActivation: out = Horner(x; c[0..8]), c = w[:,0], order 8.
// x: (512, 65536) fp32 = 33,554,432 elems. Pure streaming elementwise ->
// memory-bound. 268 MB kernel traffic; roofline ~43 us @ 6.3 TB/s.
//
// Session ledger:
//  R0 NT loads, VPT=4, one-shot:            bench 221.6 (kernel ~71 us est.)
//  R1 cached loads, VPT=8:                  bench 231.6 (kernel 81.4 us meas.)
//  R2 cached loads, VPT=4, 8 w/SIMD forced: bench 232.3 -> occupancy not it
//  R3 = R2 + NT loads:                      bench 220.3 -> LOAD POLICY was it
//    (harness poison leaves dirty L3; cached read-miss allocation evicts
//     dirty lines; NT = no-allocate but still hits resident lines.)
//
// R4 theory: kernel ~71 us = 3.8 TB/s effective, but R1 counters showed HBM
// at only 31% with L3 covering half the reads -> not BW-bound. One-shot
// waves (8 VMEM instr each, full vmcnt(0) drain between loads and stores,
// then endpgm) sag the sustained outstanding-load depth. Fix: persistent
// grid-stride (2048 blocks = 8/CU, 32 waves/CU) with register double-buffer
// prefetch — next iteration's 4 NT loads issue BEFORE current compute+store,
// so compute waits vmcnt(4), not vmcnt(0), and wave setup amortizes 4x.
// Registers: 2x4 vec4 data = 32 + addressing ~= 56 -> fits 64-VGPR bound.

typedef float f32x4 __attribute__((ext_vector_type(4)));

#define VPT   4   // f32x4 per thread per iteration (64 B)
#define ITERS 4   // iterations per wave

__global__ __launch_bounds__(256, 8) void taylor_poly_kernel(
    const f32x4* __restrict__ x,
    const float* __restrict__ w,   // 9 coefficients, c[i] = w[i]
    f32x4* __restrict__ out,
    int n4,
    int exact)                     // 1: grid*block*VPT*ITERS == n4
{
    const float c0 = w[0], c1 = w[1], c2 = w[2], c3 = w[3], c4 = w[4];
    const float c5 = w[5], c6 = w[6], c7 = w[7], c8 = w[8];

    const int tile   = blockDim.x * VPT;      // vec4 per block per iter
    const int stride = gridDim.x * tile;      // vec4 per iter, whole grid
    int base = blockIdx.x * tile + threadIdx.x;

    if (exact) {
        f32x4 cur[VPT], nxt[VPT];

#pragma unroll
        for (int k = 0; k < VPT; ++k)
            cur[k] = __builtin_nontemporal_load(&x[base + k * blockDim.x]);

#pragma unroll
        for (int it = 0; it < ITERS; ++it) {
            const int nbase = base + stride;
            if (it + 1 < ITERS) {
                // Prefetch next chunk: these 4 loads stay in flight across
                // the compute + stores below (compute waits vmcnt(4)).
#pragma unroll
                for (int k = 0; k < VPT; ++k)
                    nxt[k] = __builtin_nontemporal_load(&x[nbase + k * blockDim.x]);
            }

#pragma unroll
            for (int k = 0; k < VPT; ++k) {
                f32x4 r;
#pragma unroll
                for (int e = 0; e < 4; ++e) {
                    float xv = cur[k][e];
                    float acc = fmaf(c8, xv, c7);
                    acc = fmaf(acc, xv, c6);
                    acc = fmaf(acc, xv, c5);
                    acc = fmaf(acc, xv, c4);
                    acc = fmaf(acc, xv, c3);
                    acc = fmaf(acc, xv, c2);
                    acc = fmaf(acc, xv, c1);
                    acc = fmaf(acc, xv, c0);
                    r[e] = acc;
                }
                __builtin_nontemporal_store(r, &out[base + k * blockDim.x]);
            }

#pragma unroll
            for (int k = 0; k < VPT; ++k)
                cur[k] = nxt[k];
            base = nbase;
        }
    } else {
        // Generic guarded fallback (not taken for the bench shape).
        for (int it = 0; it < ITERS; ++it) {
#pragma unroll
            for (int k = 0; k < VPT; ++k) {
                int i = base + k * blockDim.x;
                if (i < n4) {
                    f32x4 v = __builtin_nontemporal_load(&x[i]);
                    f32x4 r;
#pragma unroll
                    for (int e = 0; e < 4; ++e) {
                        float xv = v[e];
                        float acc = fmaf(c8, xv, c7);
                        acc = fmaf(acc, xv, c6);
                        acc = fmaf(acc, xv, c5);
                        acc = fmaf(acc, xv, c4);
                        acc = fmaf(acc, xv, c3);
                        acc = fmaf(acc, xv, c2);
                        acc = fmaf(acc, xv, c1);
                        acc = fmaf(acc, xv, c0);
                        r[e] = acc;
                    }
                    __builtin_nontemporal_store(r, &out[i]);
                }
            }
            base += stride;
        }
    }
}

extern "C" void kernel_launch(void* const* d_in, const int* in_sizes, int n_in,
                              void* d_out, int out_size, void* d_ws, size_t ws_size,
                              hipStream_t stream) {
    const float* x = (const float*)d_in[0];
    const float* w = (const float*)d_in[1];
    float* out = (float*)d_out;

    int n = in_sizes[0];          // 33,554,432 — divisible by 16
    int n4 = n >> 2;              // 8,388,608 f32x4

    const int block = 256;
    const int per_block = block * VPT * ITERS;            // 4096 vec4 / block
    int grid = (n4 + per_block - 1) / per_block;          // 2048 (8 / CU)
    int exact = (grid * per_block == n4) ? 1 : 0;

    taylor_poly_kernel<<<grid, block, 0, stream>>>(
        (const f32x4*)x, w, (f32x4*)out, n4, exact);
}

// Round 5
// 219.291 us; speedup vs baseline: 1.0593x; 1.0017x over previous
//
#include <hip/hip_runtime.h>

// TaylorActivation: out = Horner(x; c[0..8]), c = w[:,0], order 8.
// x: (512, 65536) fp32 = 33,554,432 elems. Pure streaming elementwise ->
// memory-bound. 268 MB kernel traffic; roofline ~43 us @ 6.3 TB/s.
//
// Session ledger (F = fixed in-window harness fills ~150 us, calibrated
// from R1's directly-measured 81.4 us kernel dispatch):
//  R0 NT/NT one-shot:              bench 221.6  kernel ~71
//  R1 cached/NT VPT=8:             bench 231.6  kernel  81.4 (measured)
//  R2 cached/NT VPT=4 8w/SIMD:     bench 232.3  kernel ~82  -> occupancy: no effect
//  R3 NT/NT one-shot:              bench 220.3  kernel ~70  -> load policy: 10 us
//  R4 NT/NT persistent+prefetch:   bench 219.7  kernel ~69.5 -> ILP depth: no effect
//
// R5 theory: NT *path* ceiling. All rounds used NT stores. The harness
// fill writes 536 MB with PLAIN stores at 6.7 TB/s in the same dirty-cache
// environment -> plain streaming stores run full-rate. NT (no-allocate)
// stores plausibly skip L2 write-combining -> ~4 TB/s cap, matching our
// pinned ~70 us (134 MB reads + 134 MB writes @ ~4 TB/s, partly
// overlapped). Full-line overwrites need no read-for-ownership, so plain
// stores won't thrash the dirty L2/L3 the way cached LOADS did (R1/R2).
// Single-variable change from R4: stores plain, loads stay NT.

typedef float f32x4 __attribute__((ext_vector_type(4)));

#define VPT   4   // f32x4 per thread per iteration (64 B)
#define ITERS 4   // iterations per wave

__global__ __launch_bounds__(256, 8) void taylor_poly_kernel(
    const f32x4* __restrict__ x,
    const float* __restrict__ w,   // 9 coefficients, c[i] = w[i]
    f32x4* __restrict__ out,
    int n4,
    int exact)                     // 1: grid*block*VPT*ITERS == n4
{
    const float c0 = w[0], c1 = w[1], c2 = w[2], c3 = w[3], c4 = w[4];
    const float c5 = w[5], c6 = w[6], c7 = w[7], c8 = w[8];

    const int tile   = blockDim.x * VPT;      // vec4 per block per iter
    const int stride = gridDim.x * tile;      // vec4 per iter, whole grid
    int base = blockIdx.x * tile + threadIdx.x;

    if (exact) {
        f32x4 cur[VPT], nxt[VPT];

#pragma unroll
        for (int k = 0; k < VPT; ++k)
            cur[k] = __builtin_nontemporal_load(&x[base + k * blockDim.x]);

#pragma unroll
        for (int it = 0; it < ITERS; ++it) {
            const int nbase = base + stride;
            if (it + 1 < ITERS) {
                // Prefetch next chunk: stays in flight across compute+stores.
#pragma unroll
                for (int k = 0; k < VPT; ++k)
                    nxt[k] = __builtin_nontemporal_load(&x[nbase + k * blockDim.x]);
            }

#pragma unroll
            for (int k = 0; k < VPT; ++k) {
                f32x4 r;
#pragma unroll
                for (int e = 0; e < 4; ++e) {
                    float xv = cur[k][e];
                    float acc = fmaf(c8, xv, c7);
                    acc = fmaf(acc, xv, c6);
                    acc = fmaf(acc, xv, c5);
                    acc = fmaf(acc, xv, c4);
                    acc = fmaf(acc, xv, c3);
                    acc = fmaf(acc, xv, c2);
                    acc = fmaf(acc, xv, c1);
                    acc = fmaf(acc, xv, c0);
                    r[e] = acc;
                }
                // PLAIN store (R5 change): full-line overwrite, drains
                // through L2 write-combining at fill-kernel rate.
                out[base + k * blockDim.x] = r;
            }

#pragma unroll
            for (int k = 0; k < VPT; ++k)
                cur[k] = nxt[k];
            base = nbase;
        }
    } else {
        // Generic guarded fallback (not taken for the bench shape).
        for (int it = 0; it < ITERS; ++it) {
#pragma unroll
            for (int k = 0; k < VPT; ++k) {
                int i = base + k * blockDim.x;
                if (i < n4) {
                    f32x4 v = __builtin_nontemporal_load(&x[i]);
                    f32x4 r;
#pragma unroll
                    for (int e = 0; e < 4; ++e) {
                        float xv = v[e];
                        float acc = fmaf(c8, xv, c7);
                        acc = fmaf(acc, xv, c6);
                        acc = fmaf(acc, xv, c5);
                        acc = fmaf(acc, xv, c4);
                        acc = fmaf(acc, xv, c3);
                        acc = fmaf(acc, xv, c2);
                        acc = fmaf(acc, xv, c1);
                        acc = fmaf(acc, xv, c0);
                        r[e] = acc;
                    }
                    out[i] = r;
                }
            }
            base += stride;
        }
    }
}

extern "C" void kernel_launch(void* const* d_in, const int* in_sizes, int n_in,
                              void* d_out, int out_size, void* d_ws, size_t ws_size,
                              hipStream_t stream) {
    const float* x = (const float*)d_in[0];
    const float* w = (const float*)d_in[1];
    float* out = (float*)d_out;

    int n = in_sizes[0];          // 33,554,432 — divisible by 16
    int n4 = n >> 2;              // 8,388,608 f32x4

    const int block = 256;
    const int per_block = block * VPT * ITERS;            // 4096 vec4 / block
    int grid = (n4 + per_block - 1) / per_block;          // 2048 (8 / CU)
    int exact = (grid * per_block == n4) ? 1 : 0;

    taylor_poly_kernel<<<grid, block, 0, stream>>>(
        (const f32x4*)x, w, (f32x4*)out, n4, exact);
}